// Round 8
// baseline (73.776 us; speedup 1.0000x reference)
//
#include <hip/hip_runtime.h>

// CASSI forward: Y[b,m,no] = sum_l H[m,no-l] * x[b,m,no-l,l], no in [0,542)
// then Y /= max(Y); output = [Y flat | H flat].  B=8, M=512, L=31, S=1.
//
// R8 = zero-halo version of R7: ONE block per (b,m) row (4096 blocks),
// full 15,872-float row staged into 62KB LDS via global_load_lds width-16
// (fire-and-forget DMA). Block = 576 threads (9 waves); LDS caps at
// 2 blocks/CU -> 18 waves/CU (more than R7's 16). Staged bytes drop
// 290 MB -> 260 MB (halo 1.117x -> 1.0x). Lane owns one output column;
// 31 taps fully unrolled, clamped+masked (cndmask, no divergence); LDS
// gather lane-stride = 31 floats, coprime with 32 banks -> conflict-free.
// Per-block max -> ws[p] (all 4096 slots written every call, no memset);
// norm kernel re-reduces ws from L2 (16KB), scales Y in place (float4),
// appends H. 2 dispatches.

#define MDIM    512
#define LBANDS  31
#define WOUT    (MDIM + LBANDS - 1)    // 542
#define BATCH   8
#define ROWELEMS (MDIM * LBANDS)       // 15872 floats = 62 KB
#define NBLK    (BATCH * MDIM)         // 4096
#define TPB     576                    // 9 waves

__global__ __launch_bounds__(TPB) void cassi_fwd_kernel(
    const float* __restrict__ x,      // (B, M, M, L)
    const float* __restrict__ Hm,     // (M, M)
    float* __restrict__ Y,            // (B, M, WOUT), unnormalized
    float* __restrict__ bmaxs)        // ws[0..NBLK)
{
    __shared__ float xs[ROWELEMS];    // 63,488 B
    __shared__ float smax[9];

    const int tid = threadIdx.x;
    const int bm  = blockIdx.x;            // b*M + m
    const int m   = bm & (MDIM - 1);

    // ---- stage full row via global->LDS DMA (linear dest, lane-ordered) ----
    const float* __restrict__ xrow = x + (size_t)bm * ROWELEMS;
    for (int v = tid; v < ROWELEMS / 4; v += TPB)
        __builtin_amdgcn_global_load_lds(
            (const __attribute__((address_space(1))) void*)(xrow + 4 * v),
            (__attribute__((address_space(3))) void*)(xs + 4 * v),
            16, 0, 0);
    __syncthreads();   // drains vmcnt before LDS reads

    // ---- gather: lane owns col tid; 31 taps unrolled, clamped+masked ----
    float lmax = 0.0f;
    if (tid < WOUT) {
        const int no = tid;
        const float* __restrict__ hrow = Hm + m * MDIM;
        const int bn = no - (LBANDS - 1);
        float acc = 0.0f;
        #pragma unroll
        for (int t = 0; t < LBANDS; ++t) {        // l = 30 - t, n = bn + t
            const int n  = bn + t;
            int nc = n;
            nc = nc < 0 ? 0 : nc;
            nc = nc > (MDIM - 1) ? (MDIM - 1) : nc;
            const float hv = (n == nc) ? hrow[nc] : 0.0f;   // cndmask
            const float xv = xs[nc * LBANDS + (LBANDS - 1 - t)]; // in-bounds
            acc = fmaf(hv, xv, acc);
        }
        Y[(size_t)bm * WOUT + no] = acc;
        lmax = acc;
    }

    // ---- block max -> ws[p] (every slot written every call) ----
    #pragma unroll
    for (int off = 32; off > 0; off >>= 1)
        lmax = fmaxf(lmax, __shfl_down(lmax, off, 64));
    if ((tid & 63) == 0) smax[tid >> 6] = lmax;
    __syncthreads();
    if (tid == 0) {
        float bmax = smax[0];
        #pragma unroll
        for (int i = 1; i < 9; ++i) bmax = fmaxf(bmax, smax[i]);
        bmaxs[bm] = bmax;
    }
}

__global__ __launch_bounds__(1024) void cassi_norm_kernel(
    const float* __restrict__ Hm,     // (M, M)
    float* __restrict__ out,          // [Y | H], float4-aligned
    const float* __restrict__ bmaxs,  // NBLK floats (L2/L3-resident)
    int ysize4, int total4)
{
    __shared__ float sred[16];
    // ---- block-wide reduce of the 4096 maxes (16KB, cache-served) ----
    float gm = 0.0f;
    const float4* __restrict__ w4 = (const float4*)bmaxs;
    for (int i = threadIdx.x; i < NBLK / 4; i += 1024) {
        const float4 v = w4[i];
        gm = fmaxf(fmaxf(gm, fmaxf(v.x, v.y)), fmaxf(v.z, v.w));
    }
    #pragma unroll
    for (int off = 32; off > 0; off >>= 1)
        gm = fmaxf(gm, __shfl_down(gm, off, 64));
    if ((threadIdx.x & 63) == 0) sred[threadIdx.x >> 6] = gm;
    __syncthreads();
    float bmax = sred[0];
    #pragma unroll
    for (int i = 1; i < 16; ++i) bmax = fmaxf(bmax, sred[i]);
    const float inv = 1.0f / bmax;

    const int idx = blockIdx.x * 1024 + threadIdx.x;
    if (idx < ysize4) {
        float4* __restrict__ o4 = (float4*)out;
        float4 v = o4[idx];
        v.x *= inv; v.y *= inv; v.z *= inv; v.w *= inv;
        o4[idx] = v;
    } else if (idx < total4) {
        const float4* __restrict__ h4 = (const float4*)Hm;
        ((float4*)out)[idx] = h4[idx - ysize4];
    }
}

extern "C" void kernel_launch(void* const* d_in, const int* in_sizes, int n_in,
                              void* d_out, int out_size, void* d_ws, size_t ws_size,
                              hipStream_t stream) {
    const float* x  = (const float*)d_in[0];   // (8, 512, 512, 31, 1)
    const float* Hm = (const float*)d_in[1];   // (1, 512, 512, 1, 1)
    float* out = (float*)d_out;                // [Y (2,220,032) | H (262,144)]
    float* ws  = (float*)d_ws;                 // NBLK block maxes

    const int ysize4 = (BATCH * MDIM * WOUT) / 4;   // 555,008
    const int total4 = out_size / 4;                // 620,544

    cassi_fwd_kernel<<<NBLK, TPB, 0, stream>>>(x, Hm, out, ws);
    cassi_norm_kernel<<<(total4 + 1023) / 1024, 1024, 0, stream>>>(
        Hm, out, ws, ysize4, total4);
}

// Round 9
// 62.395 us; speedup vs baseline: 1.1824x; 1.1824x over previous
//
#include <hip/hip_runtime.h>

// CASSI forward: Y[b,m,no] = sum_l H[m,no-l] * x[b,m,no-l,l], no in [0,542)
// then Y /= max(Y); output = [Y flat | H flat].  B=8, M=512, L=31, S=1.
//
// R9 = R7 with halo 1.117x -> 1.059x and 16 -> 20 waves/CU:
//  - NCHUNK=2, CHUNK=288: max slice 288*31 floats = 35.7KB -> 4 blocks/CU.
//  - TPB=320 (5 FULL waves; a 288-thread block would leave a half-wave whose
//    unmapped lanes feed garbage into shfl_down during the max reduce).
//  - global_load_lds width-16 staging (linear dest, no VGPR round-trip).
//  - fully unrolled clamped+masked 31-tap gather; LDS lane-stride 31 floats,
//    coprime with 32 banks -> conflict-free (2-way aliasing = free).
//  - per-block max -> ws[p] (all 8192 slots written every call, no memset);
//    norm kernel re-reduces ws (32KB, L2), scales Y in place, appends H.

#define MDIM    512
#define LBANDS  31
#define WOUT    (MDIM + LBANDS - 1)    // 542
#define BATCH   8
#define ROWELEMS (MDIM * LBANDS)       // 15872
#define CHUNK   288
#define NCHUNK  2                      // 288 + 254 = 542
#define NBLK    (BATCH * MDIM * NCHUNK) // 8192
#define TPB     320                    // 5 full waves
#define MAXLDSF 8932                   // max slice floats (288*31=8928, +align)

__global__ __launch_bounds__(TPB, 4) void cassi_fwd_kernel(
    const float* __restrict__ x,      // (B, M, M, L)
    const float* __restrict__ Hm,     // (M, M)
    float* __restrict__ Y,            // (B, M, WOUT), unnormalized
    float* __restrict__ bmaxs)        // ws[0..NBLK)
{
    __shared__ float xs[MAXLDSF];     // 35,728 B
    __shared__ float smax[5];

    const int tid = threadIdx.x;
    const int p   = blockIdx.x;
    // XCD-aware bijective swizzle (8192 % 8 == 0): units adjacent in lb-space
    // (same row, overlapping halo) run concurrently on the same XCD's L2.
    const int lb    = ((p & 7) * (NBLK / 8)) + (p >> 3);
    const int bm    = lb >> 1;              // b*M + m
    const int chunk = lb & 1;
    const int c0    = chunk * CHUNK;
    const int m     = bm & (MDIM - 1);

    // x slice for cols [c0, c0+ncols): n in [n0, n1]
    int n0 = c0 - (LBANDS - 1); if (n0 < 0) n0 = 0;
    int n1 = c0 + CHUNK - 1;    if (n1 > MDIM - 1) n1 = MDIM - 1;
    const int gb   = (n0 * LBANDS) & ~3;        // 16B-aligned float base
    const int nvec = ((n1 + 1) * LBANDS - gb + 3) >> 2;  // stays inside row

    // ---- stage slice via global->LDS DMA (linear dest, lane-ordered) ----
    const float* __restrict__ xsl = x + (size_t)bm * ROWELEMS + gb;
    for (int v = tid; v < nvec; v += TPB)
        __builtin_amdgcn_global_load_lds(
            (const __attribute__((address_space(1))) void*)(xsl + 4 * v),
            (__attribute__((address_space(3))) void*)(xs + 4 * v),
            16, 0, 0);
    __syncthreads();   // drains vmcnt before LDS reads

    // ---- gather: lane owns col c0+tid; 31 taps unrolled, clamped+masked ----
    const int ncols = (WOUT - c0) < CHUNK ? (WOUT - c0) : CHUNK;
    float lmax = 0.0f;
    if (tid < ncols) {
        const int no = c0 + tid;
        const float* __restrict__ hrow = Hm + m * MDIM;
        const int bn = no - (LBANDS - 1);
        float acc = 0.0f;
        #pragma unroll
        for (int t = 0; t < LBANDS; ++t) {        // l = 30 - t, n = bn + t
            const int n  = bn + t;
            int nc = n;
            nc = nc < 0 ? 0 : nc;
            nc = nc > (MDIM - 1) ? (MDIM - 1) : nc;
            const float hv = (n == nc) ? hrow[nc] : 0.0f;     // cndmask
            const float xv = xs[nc * LBANDS + (LBANDS - 1 - t) - gb]; // in-slice
            acc = fmaf(hv, xv, acc);
        }
        Y[(size_t)bm * WOUT + no] = acc;
        lmax = acc;
    }

    // ---- block max -> ws[p] (every slot written every call) ----
    #pragma unroll
    for (int off = 32; off > 0; off >>= 1)
        lmax = fmaxf(lmax, __shfl_down(lmax, off, 64));
    if ((tid & 63) == 0) smax[tid >> 6] = lmax;
    __syncthreads();
    if (tid == 0) {
        float bmax = smax[0];
        #pragma unroll
        for (int i = 1; i < 5; ++i) bmax = fmaxf(bmax, smax[i]);
        bmaxs[p] = bmax;
    }
}

__global__ __launch_bounds__(1024) void cassi_norm_kernel(
    const float* __restrict__ Hm,     // (M, M)
    float* __restrict__ out,          // [Y | H], float4-aligned
    const float* __restrict__ bmaxs,  // NBLK floats (L2-resident)
    int ysize4, int total4)
{
    __shared__ float sred[16];
    // ---- block-wide reduce of the 8192 maxes (32KB, L2-served) ----
    float gm = 0.0f;
    const float4* __restrict__ w4 = (const float4*)bmaxs;
    for (int i = threadIdx.x; i < NBLK / 4; i += 1024) {
        const float4 v = w4[i];
        gm = fmaxf(fmaxf(gm, fmaxf(v.x, v.y)), fmaxf(v.z, v.w));
    }
    #pragma unroll
    for (int off = 32; off > 0; off >>= 1)
        gm = fmaxf(gm, __shfl_down(gm, off, 64));
    if ((threadIdx.x & 63) == 0) sred[threadIdx.x >> 6] = gm;
    __syncthreads();
    float bmax = sred[0];
    #pragma unroll
    for (int i = 1; i < 16; ++i) bmax = fmaxf(bmax, sred[i]);
    const float inv = 1.0f / bmax;

    const int idx = blockIdx.x * 1024 + threadIdx.x;
    if (idx < ysize4) {
        float4* __restrict__ o4 = (float4*)out;
        float4 v = o4[idx];
        v.x *= inv; v.y *= inv; v.z *= inv; v.w *= inv;
        o4[idx] = v;
    } else if (idx < total4) {
        const float4* __restrict__ h4 = (const float4*)Hm;
        ((float4*)out)[idx] = h4[idx - ysize4];
    }
}

extern "C" void kernel_launch(void* const* d_in, const int* in_sizes, int n_in,
                              void* d_out, int out_size, void* d_ws, size_t ws_size,
                              hipStream_t stream) {
    const float* x  = (const float*)d_in[0];   // (8, 512, 512, 31, 1)
    const float* Hm = (const float*)d_in[1];   // (1, 512, 512, 1, 1)
    float* out = (float*)d_out;                // [Y (2,220,032) | H (262,144)]
    float* ws  = (float*)d_ws;                 // NBLK block maxes

    const int ysize4 = (BATCH * MDIM * WOUT) / 4;   // 555,008
    const int total4 = out_size / 4;                // 620,544

    cassi_fwd_kernel<<<NBLK, TPB, 0, stream>>>(x, Hm, out, ws);
    cassi_norm_kernel<<<(total4 + 1023) / 1024, 1024, 0, stream>>>(
        Hm, out, ws, ysize4, total4);
}

// Round 10
// 56.652 us; speedup vs baseline: 1.3023x; 1.1014x over previous
//
#include <hip/hip_runtime.h>

// CASSI forward: Y[b,m,no] = sum_l H[m,no-l] * x[b,m,no-l,l], no in [0,542)
// then Y /= max(Y); output = [Y flat | H flat].  B=8, M=512, L=31, S=1.
//
// R10 = revert to R7, the measured-best configuration (56.9 us total).
// R8 (full-row, 2 blocks/CU) and R9 (CHUNK=288, TPB=320) both regressed:
// on this op cross-block MLP (>=4 independent blocks/CU, pow2 block size)
// dominates halo elimination. R7 sits at the local optimum and within ~10%
// of the streaming-traffic floor (~320 MB logical -> ~51 us + launches).
//
//  - CHUNK=256, block=256: slice 35.5KB -> 4 blocks/CU, halo 1.117x.
//  - global_load_lds width-16 staging (linear dest, no VGPR round-trip).
//  - fully unrolled clamped+masked 31-tap gather; LDS gather lane-stride =
//    31 floats, coprime with 32 banks -> conflict-free.
//  - per-block max -> ws[p] (all 12288 slots written every call, no memset,
//    no atomics); norm kernel re-reduces ws from L2 (48KB), scales Y in
//    place (float4), appends H. 2 dispatches total.
//  - bijective XCD swizzle (12288 % 8 == 0).

#define MDIM    512
#define LBANDS  31
#define WOUT    (MDIM + LBANDS - 1)    // 542
#define BATCH   8
#define ROWELEMS (MDIM * LBANDS)       // 15872
#define CHUNK   256
#define NCHUNK  3                      // 3*256 = 768 >= 542
#define NBLK    (BATCH * MDIM * NCHUNK) // 12288
#define MAXLDSF 8872                   // max slice floats (286*31=8866 +align)

__global__ __launch_bounds__(256, 4) void cassi_fwd_kernel(
    const float* __restrict__ x,      // (B, M, M, L)
    const float* __restrict__ Hm,     // (M, M)
    float* __restrict__ Y,            // (B, M, WOUT), unnormalized
    float* __restrict__ bmaxs)        // ws[0..NBLK)
{
    __shared__ float xs[MAXLDSF];     // 35,488 B
    __shared__ float smax[4];

    const int tid = threadIdx.x;
    const int p   = blockIdx.x;
    // XCD-aware bijective swizzle (12288 % 8 == 0): adjacent units (same row,
    // overlapping halos) land on the same XCD's L2 at the same time.
    const int lb    = ((p & 7) * (NBLK / 8)) + (p >> 3);
    const int bm    = lb / NCHUNK;          // b*M + m
    const int chunk = lb - bm * NCHUNK;
    const int c0    = chunk * CHUNK;
    const int m     = bm & (MDIM - 1);

    // x slice for cols [c0, ...): n in [n0, n1]
    int n0 = c0 - (LBANDS - 1); if (n0 < 0) n0 = 0;
    int n1 = c0 + CHUNK - 1;    if (n1 > MDIM - 1) n1 = MDIM - 1;
    const int gb   = (n0 * LBANDS) & ~3;        // 16B-aligned float base
    const int nvec = ((n1 + 1) * LBANDS - gb + 3) >> 2;  // stays inside row

    // ---- stage slice via global->LDS DMA (linear dest, lane-ordered) ----
    const float* __restrict__ xsl = x + (size_t)bm * ROWELEMS + gb;
    for (int v = tid; v < nvec; v += 256)
        __builtin_amdgcn_global_load_lds(
            (const __attribute__((address_space(1))) void*)(xsl + 4 * v),
            (__attribute__((address_space(3))) void*)(xs + 4 * v),
            16, 0, 0);
    __syncthreads();   // drains vmcnt before LDS reads

    // ---- gather: lane owns col c0+tid; 31 taps unrolled, clamped+masked ----
    const int no = c0 + tid;
    const float* __restrict__ hrow = Hm + m * MDIM;
    const int bn = no - (LBANDS - 1);
    float acc = 0.0f;
    #pragma unroll
    for (int t = 0; t < LBANDS; ++t) {          // l = 30 - t, n = bn + t
        const int n  = bn + t;
        int nc = n;
        nc = nc < 0 ? 0 : nc;
        nc = nc > (MDIM - 1) ? (MDIM - 1) : nc;
        const float hv = (n == nc) ? hrow[nc] : 0.0f;     // cndmask, no branch
        const float xv = xs[nc * LBANDS + (LBANDS - 1 - t) - gb]; // in [n0,n1]
        acc = fmaf(hv, xv, acc);
    }
    float lmax = 0.0f;
    if (no < WOUT) {
        Y[(size_t)bm * WOUT + no] = acc;
        lmax = acc;
    }

    // ---- block max -> ws[p] (every slot written every call) ----
    #pragma unroll
    for (int off = 32; off > 0; off >>= 1)
        lmax = fmaxf(lmax, __shfl_down(lmax, off, 64));
    if ((tid & 63) == 0) smax[tid >> 6] = lmax;
    __syncthreads();
    if (tid == 0)
        bmaxs[p] = fmaxf(fmaxf(smax[0], smax[1]), fmaxf(smax[2], smax[3]));
}

__global__ __launch_bounds__(1024) void cassi_norm_kernel(
    const float* __restrict__ Hm,     // (M, M)
    float* __restrict__ out,          // [Y | H], float4-aligned
    const float* __restrict__ bmaxs,  // NBLK floats (L2-resident)
    int ysize4, int total4)
{
    __shared__ float sred[16];
    // ---- block-wide reduce of the 12288 maxes (48KB, L2-served) ----
    float gm = 0.0f;
    const float4* __restrict__ w4 = (const float4*)bmaxs;
    for (int i = threadIdx.x; i < NBLK / 4; i += 1024) {
        const float4 v = w4[i];
        gm = fmaxf(fmaxf(gm, fmaxf(v.x, v.y)), fmaxf(v.z, v.w));
    }
    #pragma unroll
    for (int off = 32; off > 0; off >>= 1)
        gm = fmaxf(gm, __shfl_down(gm, off, 64));
    if ((threadIdx.x & 63) == 0) sred[threadIdx.x >> 6] = gm;
    __syncthreads();
    float bmax = sred[0];
    #pragma unroll
    for (int i = 1; i < 16; ++i) bmax = fmaxf(bmax, sred[i]);
    const float inv = 1.0f / bmax;

    const int idx = blockIdx.x * 1024 + threadIdx.x;
    if (idx < ysize4) {
        float4* __restrict__ o4 = (float4*)out;
        float4 v = o4[idx];
        v.x *= inv; v.y *= inv; v.z *= inv; v.w *= inv;
        o4[idx] = v;
    } else if (idx < total4) {
        const float4* __restrict__ h4 = (const float4*)Hm;
        ((float4*)out)[idx] = h4[idx - ysize4];
    }
}

extern "C" void kernel_launch(void* const* d_in, const int* in_sizes, int n_in,
                              void* d_out, int out_size, void* d_ws, size_t ws_size,
                              hipStream_t stream) {
    const float* x  = (const float*)d_in[0];   // (8, 512, 512, 31, 1)
    const float* Hm = (const float*)d_in[1];   // (1, 512, 512, 1, 1)
    float* out = (float*)d_out;                // [Y (2,220,032) | H (262,144)]
    float* ws  = (float*)d_ws;                 // NBLK block maxes

    const int ysize4 = (BATCH * MDIM * WOUT) / 4;   // 555,008
    const int total4 = out_size / 4;                // 620,544

    cassi_fwd_kernel<<<NBLK, 256, 0, stream>>>(x, Hm, out, ws);
    cassi_norm_kernel<<<(total4 + 1023) / 1024, 1024, 0, stream>>>(
        Hm, out, ws, ysize4, total4);
}